// Round 9
// baseline (78.643 us; speedup 1.0000x reference)
//
#include <hip/hip_runtime.h>
#include <hip/hip_fp16.h>
#include <cstdint>
#include <cstddef>

// FastGRNN cell, MI355X fp16-MFMA, v9.
// prep:   weights f32->f16 into wb.
// stage1: 768 blocks x 256 thr (3 blocks/CU via 48KB LDS), BM=64 BN=128 K=1024.
//         E/O register prefetch + lgkmcnt-only barriers (vmcnt never drained at
//         barriers; loads for tile t+2 stay in flight). rbuf[8192][768] f16.
// stage2: pre = [wx | uh0+uh1] @ [W2|U2]^T (K=512), fused sigmoid/tanh epilogue.

typedef _Float16 half8 __attribute__((ext_vector_type(8)));
typedef float f32x4 __attribute__((ext_vector_type(4)));

#define DIN 1024
#define DH 2048
#define RK 256
#define RBLD 768
// wb half-offsets
#define OFF_W1H 0
#define OFF_U1H 262144
#define OFF_W2H 786432
#define OFF_U2H 1310720

__device__ __forceinline__ half8 cvt8(const float4 a, const float4 b) {
  half8 h;
  h[0] = (_Float16)a.x; h[1] = (_Float16)a.y; h[2] = (_Float16)a.z; h[3] = (_Float16)a.w;
  h[4] = (_Float16)b.x; h[5] = (_Float16)b.y; h[6] = (_Float16)b.z; h[7] = (_Float16)b.w;
  return h;
}

// ---------------- prep: weights f32 -> f16 ----------------------------------
__global__ __launch_bounds__(256)
void fgrnn_prep(const float* __restrict__ W1, const float* __restrict__ U1,
                const float* __restrict__ W2, const float* __restrict__ U2,
                _Float16* __restrict__ wb) {
  const int q = blockIdx.x * 256 + threadIdx.x;
  const float* src;
  int rel;
  if (q < 65536) { src = W1; rel = q; }
  else if (q < 196608) { src = U1; rel = q - 65536; }
  else if (q < 327680) { src = W2; rel = q - 196608; }
  else { src = U2; rel = q - 327680; }
  const float4 v = reinterpret_cast<const float4*>(src)[rel];
  union { _Float16 h[4]; uint2 u; } cv;
  cv.h[0] = (_Float16)v.x; cv.h[1] = (_Float16)v.y;
  cv.h[2] = (_Float16)v.z; cv.h[3] = (_Float16)v.w;
  reinterpret_cast<uint2*>(wb)[q] = cv.u;
}

// ---------------- stage 1: BM=64, BN=128, K=1024 (16 iters) -----------------
// 256 thr = 4 waves 2x2; wave tile 32x64 (acc[2][4]).
// Double-buffered 48KB LDS; one lgkmcnt-only barrier per iter.
__global__ __launch_bounds__(256, 3)
void fgrnn_stage1(const float* __restrict__ x, const float* __restrict__ h,
                  const _Float16* __restrict__ wb, _Float16* __restrict__ rbuf) {
  __shared__ _Float16 As[2 * 64 * 64];    // 16 KB
  __shared__ _Float16 Bs[2 * 128 * 64];   // 32 KB

  const int bid = blockIdx.x;
  const int L = (bid & 7) * 96 + (bid >> 3);   // XCD chunk swizzle (768 = 8*96)
  const int g = L >> 8;                        // 0: x@W1, 1: h@U1 lo-k, 2: hi-k
  const int rem = L & 255;
  const int ncol = rem >> 7;                   // 0,1
  const int mtile = rem & 127;
  const bool isx = (g == 0);
  const float* A = isx ? x : h;
  const int KA = isx ? DIN : DH;
  const int kbase = (g == 2) ? 1024 : 0;
  const _Float16* Bw = wb + (isx ? OFF_W1H : OFF_U1H) + (size_t)(ncol * 128) * KA;
  const int row0 = mtile * 64;
  const int colbase = g * 256 + ncol * 128;

  const int tid = threadIdx.x;
  const int lane = tid & 63;
  const int w = tid >> 6;
  const int wr = w >> 1, wc = w & 1;
  const int sr = tid >> 3;        // 0..31
  const int sc = (tid & 7) * 8;

  f32x4 acc[2][4];
#pragma unroll
  for (int i = 0; i < 2; ++i)
#pragma unroll
    for (int j = 0; j < 4; ++j) acc[i][j] = (f32x4){0.f, 0.f, 0.f, 0.f};

  // E/O named prefetch sets (static indexing only)
  float4 raE[2][2], raO[2][2];
  half8 rbE[4], rbO[4];

  auto LOADG = [&](float4 (&ra)[2][2], half8 (&rb)[4], int it) {
    const int k0 = kbase + it * 64;
#pragma unroll
    for (int j = 0; j < 2; ++j) {
      const float* s = A + (size_t)(row0 + j * 32 + sr) * KA + k0 + sc;
      ra[j][0] = *reinterpret_cast<const float4*>(s);
      ra[j][1] = *reinterpret_cast<const float4*>(s + 4);
    }
#pragma unroll
    for (int j = 0; j < 4; ++j)
      rb[j] = *reinterpret_cast<const half8*>(Bw + (size_t)(j * 32 + sr) * KA + k0 + sc);
  };
  auto STORE = [&](const float4 (&ra)[2][2], const half8 (&rb)[4],
                   _Float16* as, _Float16* bs) {
#pragma unroll
    for (int j = 0; j < 2; ++j) {
      const int r = j * 32 + sr;
      *reinterpret_cast<half8*>(&as[r * 64 + (sc ^ ((r & 7) << 3))]) =
          cvt8(ra[j][0], ra[j][1]);
    }
#pragma unroll
    for (int j = 0; j < 4; ++j) {
      const int r = j * 32 + sr;
      *reinterpret_cast<half8*>(&bs[r * 64 + (sc ^ ((r & 7) << 3))]) = rb[j];
    }
  };
  auto COMPUTE = [&](const _Float16* as, const _Float16* bs) {
#pragma unroll
    for (int kk = 0; kk < 64; kk += 32) {
      half8 af[2], bf[4];
#pragma unroll
      for (int mi = 0; mi < 2; ++mi) {
        const int r = wr * 32 + mi * 16 + (lane & 15);
        af[mi] = *reinterpret_cast<const half8*>(
            &as[r * 64 + ((kk + 8 * (lane >> 4)) ^ ((r & 7) << 3))]);
      }
#pragma unroll
      for (int ni = 0; ni < 4; ++ni) {
        const int r = wc * 64 + ni * 16 + (lane & 15);
        bf[ni] = *reinterpret_cast<const half8*>(
            &bs[r * 64 + ((kk + 8 * (lane >> 4)) ^ ((r & 7) << 3))]);
      }
#pragma unroll
      for (int mi = 0; mi < 2; ++mi)
#pragma unroll
        for (int ni = 0; ni < 4; ++ni)
          acc[mi][ni] =
              __builtin_amdgcn_mfma_f32_16x16x32_f16(af[mi], bf[ni], acc[mi][ni], 0, 0, 0);
    }
  };
  auto BAR = [&]() {
    asm volatile("s_waitcnt lgkmcnt(0)" ::: "memory");  // LDS writes visible
    __builtin_amdgcn_s_barrier();                       // vmcnt stays in flight
    asm volatile("" ::: "memory");
  };

  _Float16* as0 = As;
  _Float16* as1 = As + 64 * 64;
  _Float16* bs0 = Bs;
  _Float16* bs1 = Bs + 128 * 64;

  LOADG(raE, rbE, 0);
  LOADG(raO, rbO, 1);             // stays in flight across prologue barrier
  STORE(raE, rbE, as0, bs0);      // compiler waits only on E-set loads
  BAR();

#pragma unroll 1
  for (int it2 = 0; it2 < 16; it2 += 2) {
    if (it2 + 2 < 16) LOADG(raE, rbE, it2 + 2);
    COMPUTE(as0, bs0);
    STORE(raO, rbO, as1, bs1);
    BAR();
    if (it2 + 3 < 16) LOADG(raO, rbO, it2 + 3);
    COMPUTE(as1, bs1);
    if (it2 + 2 < 16) STORE(raE, rbE, as0, bs0);
    BAR();
  }

  // D layout (16x16 family): row = 4*(lane>>4)+e, col = lane&15.
#pragma unroll
  for (int mi = 0; mi < 2; ++mi)
#pragma unroll
    for (int ni = 0; ni < 4; ++ni)
#pragma unroll
      for (int e = 0; e < 4; ++e) {
        const int row = row0 + wr * 32 + mi * 16 + 4 * (lane >> 4) + e;
        const int col = colbase + wc * 64 + ni * 16 + (lane & 15);
        rbuf[(size_t)row * RBLD + col] = (_Float16)acc[mi][ni][e];
      }
}

// ---------------- stage 2: pre = [wx | uh0+uh1] @ [W2|U2]^T, K=512 ----------
// 2048 blocks x 256 threads. BM=64, BN=128, BK=64, 8 iters; 4 waves 2x2,
// wave tile 32x64 (acc[2][4]). uh panel add fused into A staging.
__global__ __launch_bounds__(256)
void fgrnn_stage2(const _Float16* __restrict__ rbuf, const _Float16* __restrict__ wb,
                  const float* __restrict__ state,
                  const float* __restrict__ bg, const float* __restrict__ bu,
                  const float* __restrict__ zeta, const float* __restrict__ nu,
                  float* __restrict__ out) {
  const int bid = blockIdx.x;
  const int L = (bid & 7) * 256 + (bid >> 3);   // XCD swizzle: mtile-banded
  const int mtile = L >> 4;   // 0..127
  const int ntile = L & 15;   // 0..15
  const int row0 = mtile * 64;
  const int col0 = ntile * 128;
  const _Float16* W2h = wb + OFF_W2H;
  const _Float16* U2h = wb + OFF_U2H;

  __shared__ _Float16 As[64 * 64];
  __shared__ _Float16 Bs[128 * 64];

  const int tid = threadIdx.x;
  const int lane = tid & 63;
  const int w = tid >> 6;
  const int wr = w >> 1, wc = w & 1;

  f32x4 acc[2][4];
#pragma unroll
  for (int i = 0; i < 2; ++i)
#pragma unroll
    for (int j = 0; j < 4; ++j) acc[i][j] = (f32x4){0.f, 0.f, 0.f, 0.f};

  const int sr = tid >> 3;      // 0..31
  const int sc = (tid & 7) * 8;

  half8 pa[2], pa2[2], pb[4];

  auto LOADG = [&](int it) {
    const int k0 = it * 64;
    const bool iswx = (k0 < 256);
#pragma unroll
    for (int j = 0; j < 2; ++j) {
      const _Float16* p = rbuf + (size_t)(row0 + j * 32 + sr) * RBLD + k0 + sc;
      pa[j] = *reinterpret_cast<const half8*>(p);
      if (!iswx) pa2[j] = *reinterpret_cast<const half8*>(p + 256);  // uh1 panel
    }
    const _Float16* Bh = iswx ? W2h : U2h;
    const int kb = k0 & 255;
#pragma unroll
    for (int j = 0; j < 4; ++j)
      pb[j] = *reinterpret_cast<const half8*>(Bh + (size_t)(col0 + j * 32 + sr) * RK + kb + sc);
  };
  auto STORE = [&](int it) {
    const int k0 = it * 64;
#pragma unroll
    for (int j = 0; j < 2; ++j) {
      half8 v = pa[j];
      if (k0 >= 256) v = v + pa2[j];   // uh = uh0 + uh1 (v_pk_add_f16)
      const int r = j * 32 + sr;
      *reinterpret_cast<half8*>(&As[r * 64 + (sc ^ ((r & 7) << 3))]) = v;
    }
#pragma unroll
    for (int j = 0; j < 4; ++j) {
      const int r = j * 32 + sr;
      *reinterpret_cast<half8*>(&Bs[r * 64 + (sc ^ ((r & 7) << 3))]) = pb[j];
    }
  };

  LOADG(0);
  STORE(0);
  __syncthreads();

  for (int it = 0; it < 8; ++it) {
    const bool more = (it + 1 < 8);
    if (more) LOADG(it + 1);
#pragma unroll
    for (int kk = 0; kk < 64; kk += 32) {
      half8 af[2], bf[4];
#pragma unroll
      for (int mi = 0; mi < 2; ++mi) {
        const int r = wr * 32 + mi * 16 + (lane & 15);
        af[mi] = *reinterpret_cast<const half8*>(
            &As[r * 64 + ((kk + 8 * (lane >> 4)) ^ ((r & 7) << 3))]);
      }
#pragma unroll
      for (int ni = 0; ni < 4; ++ni) {
        const int r = wc * 64 + ni * 16 + (lane & 15);
        bf[ni] = *reinterpret_cast<const half8*>(
            &Bs[r * 64 + ((kk + 8 * (lane >> 4)) ^ ((r & 7) << 3))]);
      }
#pragma unroll
      for (int mi = 0; mi < 2; ++mi)
#pragma unroll
        for (int ni = 0; ni < 4; ++ni)
          acc[mi][ni] =
              __builtin_amdgcn_mfma_f32_16x16x32_f16(af[mi], bf[ni], acc[mi][ni], 0, 0, 0);
    }
    if (more) {
      __syncthreads();
      STORE(it + 1);
    }
    __syncthreads();
  }

  // Fused epilogue (fast exp2/rcp; asymptotes correct)
  const float LOG2E = 1.44269504f;
  const float sz = __builtin_amdgcn_rcpf(1.f + __builtin_amdgcn_exp2f(-zeta[0] * LOG2E));
  const float sn = __builtin_amdgcn_rcpf(1.f + __builtin_amdgcn_exp2f(-nu[0] * LOG2E));
#pragma unroll
  for (int mi = 0; mi < 2; ++mi)
#pragma unroll
    for (int ni = 0; ni < 4; ++ni) {
      const int col = col0 + wc * 64 + ni * 16 + (lane & 15);
      const float bgc = bg[col];
      const float buc = bu[col];
#pragma unroll
      for (int e = 0; e < 4; ++e) {
        const int row = row0 + wr * 32 + mi * 16 + 4 * (lane >> 4) + e;
        const float pre = acc[mi][ni][e];
        const float zg =
            __builtin_amdgcn_rcpf(1.f + __builtin_amdgcn_exp2f(-(pre + bgc) * LOG2E));
        const float hc =
            1.f - 2.f * __builtin_amdgcn_rcpf(
                            1.f + __builtin_amdgcn_exp2f((pre + buc) * (2.f * LOG2E)));
        const float sv = state[(size_t)row * DH + col];
        out[(size_t)row * DH + col] = zg * sv + (sz * (1.f - zg) + sn) * hc;
      }
    }
}

extern "C" void kernel_launch(void* const* d_in, const int* in_sizes, int n_in,
                              void* d_out, int out_size, void* d_ws, size_t ws_size,
                              hipStream_t stream) {
  const float* input = (const float*)d_in[0];
  const float* state = (const float*)d_in[1];
  const float* W1 = (const float*)d_in[2];
  const float* W2 = (const float*)d_in[3];
  const float* U1 = (const float*)d_in[4];
  const float* U2 = (const float*)d_in[5];
  const float* bg = (const float*)d_in[6];
  const float* bu = (const float*)d_in[7];
  const float* zeta = (const float*)d_in[8];
  const float* nu = (const float*)d_in[9];
  float* out = (float*)d_out;

  _Float16* rbuf = (_Float16*)d_ws;                     // 8192*768*2 = 12.6 MB
  _Float16* wb = rbuf + (size_t)8192 * RBLD;            // +3.67 MB f16 weights

  fgrnn_prep<<<1792, 256, 0, stream>>>(W1, U1, W2, U2, wb);
  fgrnn_stage1<<<768, 256, 0, stream>>>(input, state, wb, rbuf);
  fgrnn_stage2<<<2048, 256, 0, stream>>>(rbuf, wb, state, bg, bu, zeta, nu, out);
}